// Round 14
// baseline (1190.731 us; speedup 1.0000x reference)
//
#include <hip/hip_runtime.h>

// GGNN layer, B=64, N=512, D=512, steps=2. Numerics = rounds 6-10 pass set
// (fp16 + power-of-2 scaling, split passes on r/hc path; absmax 131072).
// r13: B-operand (weights / ht, L2-resident) loaded DIRECTLY global->VGPR
// (coalesced: [col][k] rows, 4-lane groups cover full 128B lines). This
// empties the global->LDS staging path of B and enables BN=512 (ncolb=1):
// A staged exactly once per pass (32 MB/pass vs r8's 128).
// Tile 64x512, 8 waves of 64x64, acc 64 VGPR, LDS = single 8 KiB A-buffer,
// m97 two-syncthreads pattern (race-free), 2 blocks/CU via launch_bounds.

#define LD 512
#define NNL ((long)LD * LD)

typedef unsigned short u16;
typedef _Float16 f16;
typedef f16 f16x8 __attribute__((ext_vector_type(8)));
typedef float f32x4 __attribute__((ext_vector_type(4)));

__device__ __forceinline__ u16 f2h(float f) { f16 h = (f16)f; return *(u16*)&h; }
__device__ __forceinline__ float h2f(u16 b) { f16 h = *(f16*)&b; return (float)h; }

__device__ __forceinline__ void gload16(const void* g, void* l) {
  __builtin_amdgcn_global_load_lds(
      (const __attribute__((address_space(1))) void*)g,
      (__attribute__((address_space(3))) void*)l, 16, 0, 0);
}

// ---------------- f32 -> f16 single ----------------
__global__ void cvt_f16(const float* __restrict__ in, u16* __restrict__ out, int n4) {
  int i = blockIdx.x * blockDim.x + threadIdx.x;
  if (i >= n4) return;
  float4 v = reinterpret_cast<const float4*>(in)[i];
  ushort4 o;
  o.x = f2h(v.x); o.y = f2h(v.y); o.z = f2h(v.z); o.w = f2h(v.w);
  reinterpret_cast<ushort4*>(out)[i] = o;
}

// ---------------- f32 -> f16 hi/lo split ----------------
__global__ void cvt2h(const float* __restrict__ in, u16* __restrict__ ohi,
                      u16* __restrict__ olo, int n4) {
  int i = blockIdx.x * blockDim.x + threadIdx.x;
  if (i >= n4) return;
  float4 v = reinterpret_cast<const float4*>(in)[i];
  ushort4 h, l;
  h.x = f2h(v.x); l.x = f2h(v.x - h2f(h.x));
  h.y = f2h(v.y); l.y = f2h(v.y - h2f(h.y));
  h.z = f2h(v.z); l.z = f2h(v.z - h2f(h.z));
  h.w = f2h(v.w); l.w = f2h(v.w - h2f(h.w));
  reinterpret_cast<ushort4*>(ohi)[i] = h;
  reinterpret_cast<ushort4*>(olo)[i] = l;
}

// ------- weight f32 [K][N] -> f16 single (scaled), transposed [N][K] -------
__global__ void wconv1(const float* __restrict__ in, u16* __restrict__ out, float scale) {
  __shared__ float sm[32][33];
  int tx = threadIdx.x & 31, ty = threadIdx.x >> 5;
  int k0 = blockIdx.y * 32, n0 = blockIdx.x * 32;
#pragma unroll
  for (int i = 0; i < 32; i += 8)
    sm[ty + i][tx] = in[(size_t)(k0 + ty + i) * LD + n0 + tx];
  __syncthreads();
#pragma unroll
  for (int i = 0; i < 32; i += 8)
    out[(size_t)(n0 + ty + i) * LD + k0 + tx] = f2h(sm[tx][ty + i] * scale);
}

// ------- weight f32 [K][N] -> f16 hi/lo (scaled), transposed [N][K] -------
__global__ void wconv2h(const float* __restrict__ in, u16* __restrict__ ohi,
                        u16* __restrict__ olo, float scale) {
  __shared__ float sm[32][33];
  int tx = threadIdx.x & 31, ty = threadIdx.x >> 5;
  int k0 = blockIdx.y * 32, n0 = blockIdx.x * 32;
#pragma unroll
  for (int i = 0; i < 32; i += 8)
    sm[ty + i][tx] = in[(size_t)(k0 + ty + i) * LD + n0 + tx];
  __syncthreads();
#pragma unroll
  for (int i = 0; i < 32; i += 8) {
    float v = sm[tx][ty + i] * scale;
    u16 hi = f2h(v);
    size_t o = (size_t)(n0 + ty + i) * LD + k0 + tx;
    ohi[o] = hi;
    olo[o] = f2h(v - h2f(hi));
  }
}

// -------- u16 transpose per batch: [B][N][D] -> [B][D][N] --------
__global__ void transp16(const u16* __restrict__ in, u16* __restrict__ out) {
  __shared__ u16 sm[64][65];
  int b = blockIdx.z;
  int n0 = blockIdx.y * 64, d0 = blockIdx.x * 64;
  int lane = threadIdx.x & 63, grp = threadIdx.x >> 6;
  const u16* src = in + ((size_t)b * LD + n0) * LD + d0;
#pragma unroll
  for (int i = grp; i < 64; i += 4)
    sm[i][lane] = src[(size_t)i * LD + lane];
  __syncthreads();
  u16* dst = out + ((size_t)b * LD + d0) * LD + n0;
#pragma unroll
  for (int i = grp; i < 64; i += 4)
    dst[(size_t)i * LD + lane] = sm[lane][i];
}

// ------- fp16 MFMA GEMM: tile 64x512, A via LDS (8 KiB), B direct to regs -------
// EPI 0 ENC: v=relu(acc+b1)*mask[row]   -> outf, o16=v*2^-4
// EPI 1 A  : v=acc+b1*2^-4 (batched)    -> o16=hi, o16b=lo
// EPI 2 Z  : v=relu(acc+b1)             -> o16=v*2^-4
// EPI 3 R  : v=relu(acc+b1)*hf32[idx]   -> o16=hi(v*2^-12), o16b=lo
// EPI 4 GRU: hc=tanh(acc+b1)*mask; z=16*z16[idx]; hn=(1-z)*hf32+z*hc -> outf, o16
struct Desc {
  const u16* A[6];
  const u16* B[6];
  const float* bias1;
  const float* mask;
  const float* hf32;
  const u16* z16;
  float* outf;
  u16* o16;
  u16* o16b;
};

template <int EPI, int NA>
__global__ __launch_bounds__(512, 4) void gemw(Desc d) {
  __shared__ __align__(16) u16 As[64 * 64];  // one 64x64 f16 A-tile, 8 KiB

  const int t = threadIdx.x;
  const int lane = t & 63;
  const int wid = t >> 6;  // wave -> 64-col strip

  // XCD-aware swizzle over 512 blocks (64/XCD); rowb -> XCD invariant.
  const int id = (int)blockIdx.x;
  const int rowb = (id & 7) * 64 + (id >> 3);  // 0..511
  size_t baseA, baseB;
  int rowBase0;
  if (EPI == 1) {
    const size_t bz = (size_t)(rowb >> 3);
    baseA = bz * NNL + (size_t)(rowb & 7) * 64 * LD;
    baseB = bz * NNL;
    rowBase0 = (int)bz * 512 + (rowb & 7) * 64;
  } else {
    baseA = (size_t)rowb * 64 * LD;
    baseB = 0;
    rowBase0 = rowb * 64;
  }

  // staging: thread t stages 16B chunk c=t: row r=c>>3, dest chunk g=c&7,
  // source k-chunk g^(r&7)  (rule 21: linear LDS dest, pre-swizzled source)
  const int sr = t >> 3, sg = t & 7;
  const int ssrc = (sg ^ (sr & 7)) * 8;

  // ds-read: frag row R=(lane&15)+16i; chunk (ks*4+lk)^(R&7); R&7==lane&7
  const int lk = lane >> 4;
  int aoff[2];
#pragma unroll
  for (int ks = 0; ks < 2; ++ks)
    aoff[ks] = (lane & 15) * 64 + (((ks * 4 + lk) ^ (lane & 7)) * 8);

  // B columns this lane reads: col = wid*64 + j*16 + (lane&15)
  const int colLane = wid * 64 + (lane & 15);

  f32x4 acc[4][4] = {};

  for (int s = 0; s < NA; ++s) {
    const u16* Ap = d.A[s] + baseA;
    const u16* Bp = d.B[s] + baseB;
    for (int kt = 0; kt < 8; ++kt) {
      const int kb = kt * 64;
      gload16(Ap + (size_t)sr * LD + kb + ssrc, As + t * 8);
      __syncthreads();  // stage landed for all
#pragma unroll
      for (int ks = 0; ks < 2; ++ks) {
        f16x8 af[4], bf[4];
#pragma unroll
        for (int i = 0; i < 4; ++i)
          af[i] = *(const f16x8*)&As[aoff[ks] + i * 1024];
#pragma unroll
        for (int j = 0; j < 4; ++j)
          bf[j] = *(const f16x8*)(Bp + (size_t)(colLane + j * 16) * LD + kb + ks * 32 + lk * 8);
#pragma unroll
        for (int i = 0; i < 4; ++i)
#pragma unroll
          for (int j = 0; j < 4; ++j)
            acc[i][j] = __builtin_amdgcn_mfma_f32_16x16x32_f16(af[i], bf[j], acc[i][j], 0, 0, 0);
      }
      __syncthreads();  // reads done before next stage overwrites
    }
  }

  // epilogue: C/D layout col=lane&15, row=(lane>>4)*4+reg [m89-verified]
  const float S4 = 0.0625f;          // 2^-4
  const float S12 = 2.44140625e-4f;  // 2^-12
  const int rowBase = rowBase0 + (lane >> 4) * 4;
  const int colBase = wid * 64 + (lane & 15);
#pragma unroll
  for (int i = 0; i < 4; ++i) {
#pragma unroll
    for (int j = 0; j < 4; ++j) {
      const int col = colBase + j * 16;
      const float bv = d.bias1[col];
#pragma unroll
      for (int r = 0; r < 4; ++r) {
        const int row = rowBase + i * 16 + r;
        const size_t idx = (size_t)row * LD + col;
        const float a = acc[i][j][r];
        if (EPI == 0) {
          float v = fmaxf(a + bv, 0.0f) * d.mask[row];
          d.outf[idx] = v;
          d.o16[idx] = f2h(v * S4);
        } else if (EPI == 1) {
          float v = a + bv * S4;
          u16 hi = f2h(v);
          d.o16[idx] = hi;
          d.o16b[idx] = f2h(v - h2f(hi));
        } else if (EPI == 2) {
          float v = fmaxf(a + bv, 0.0f);
          d.o16[idx] = f2h(v * S4);
        } else if (EPI == 3) {
          float v = fmaxf(a + bv, 0.0f) * d.hf32[idx];
          u16 hi = f2h(v * S12);
          d.o16[idx] = hi;
          float rec = h2f(hi) * 4096.0f;
          d.o16b[idx] = f2h((v - rec) * S12);
        } else {
          float hc = tanhf(a + bv) * d.mask[row];
          float z = 16.0f * h2f(d.z16[idx]);
          float h = d.hf32[idx];
          float hn = (1.0f - z) * h + z * hc;
          d.outf[idx] = hn;
          d.o16[idx] = f2h(hn * S4);
        }
      }
    }
  }
}

extern "C" void kernel_launch(void* const* d_in, const int* in_sizes, int n_in,
                              void* d_out, int out_size, void* d_ws, size_t ws_size,
                              hipStream_t stream) {
  const float* x    = (const float*)d_in[0];
  const float* adj  = (const float*)d_in[1];
  const float* mask = (const float*)d_in[2];
  const float* Wenc = (const float*)d_in[3];
  const float* benc = (const float*)d_in[4];
  const float* Wz   = (const float*)d_in[5];
  const float* Uz   = (const float*)d_in[6];
  const float* bz_  = (const float*)d_in[7];
  const float* Wr   = (const float*)d_in[8];
  const float* Ur   = (const float*)d_in[9];
  const float* br_  = (const float*)d_in[10];
  const float* Wh   = (const float*)d_in[11];
  const float* Uh   = (const float*)d_in[12];
  const float* bh_  = (const float*)d_in[13];
  const float* ba_  = (const float*)d_in[14];

  float* hf = (float*)d_out;  // h in f32 across steps (64 MiB)

  const size_t SZ  = (size_t)64 * 512 * 512 * sizeof(u16);  // 32 MiB
  const size_t WSZ = (size_t)LD * LD * sizeof(u16);         // 0.5 MiB
  const size_t NEED = 7 * SZ + 11 * WSZ;                    // 229.5 MiB
  if (ws_size < NEED) return;

  char* p = (char*)d_ws;
  u16* adj16 = (u16*)p; p += SZ;
  u16* h16   = (u16*)p; p += SZ;   // h * 2^-4
  u16* a_hi  = (u16*)p; p += SZ;   // a*2^-4 hi ; aliased: x_hi before encoder
  u16* a_lo  = (u16*)p; p += SZ;   // a*2^-4 lo ; aliased: x_lo before encoder
  u16* zht   = (u16*)p; p += SZ;   // h^T*2^-4 (transp..A), then z*2^-4 (Z..GRU)
  u16* rh_hi = (u16*)p; p += SZ;   // rh*2^-12 hi
  u16* rh_lo = (u16*)p; p += SZ;   // rh*2^-12 lo
  u16* w     = (u16*)p;
  u16* We_h = w + 0 * LD * LD;  u16* We_l = w + 1 * LD * LD;   // x1
  u16* Wz1  = w + 2 * LD * LD;                                  // x16
  u16* Uz1  = w + 3 * LD * LD;                                  // x16
  u16* Wr_h = w + 4 * LD * LD;  u16* Wr_l = w + 5 * LD * LD;   // x16
  u16* Ur1  = w + 6 * LD * LD;                                  // x16
  u16* Wh_h = w + 7 * LD * LD;  u16* Wh_l = w + 8 * LD * LD;   // x16
  u16* Uh_h = w + 9 * LD * LD;  u16* Uh_l = w + 10 * LD * LD;  // x4096
  u16* x_hi = a_hi;
  u16* x_lo = a_lo;

  const int NELT = 64 * 512 * 512;
  cvt2h<<<NELT / 4 / 256, 256, 0, stream>>>(x, x_hi, x_lo, NELT / 4);
  cvt_f16<<<NELT / 4 / 256, 256, 0, stream>>>(adj, adj16, NELT / 4);

  dim3 wg(16, 16);
  wconv2h<<<wg, 256, 0, stream>>>(Wenc, We_h, We_l, 1.0f);
  wconv1<<<wg, 256, 0, stream>>>(Wz, Wz1, 16.0f);
  wconv1<<<wg, 256, 0, stream>>>(Uz, Uz1, 16.0f);
  wconv2h<<<wg, 256, 0, stream>>>(Wr, Wr_h, Wr_l, 16.0f);
  wconv1<<<wg, 256, 0, stream>>>(Ur, Ur1, 16.0f);
  wconv2h<<<wg, 256, 0, stream>>>(Wh, Wh_h, Wh_l, 16.0f);
  wconv2h<<<wg, 256, 0, stream>>>(Uh, Uh_h, Uh_l, 4096.0f);

  // ENC (x3): h0 = mask*relu(x@Wenc+benc)
  {
    Desc d{};
    d.A[0] = x_hi; d.B[0] = We_h;
    d.A[1] = x_hi; d.B[1] = We_l;
    d.A[2] = x_lo; d.B[2] = We_h;
    d.bias1 = benc; d.mask = mask; d.outf = hf; d.o16 = h16;
    gemw<0, 3><<<512, 512, 0, stream>>>(d);
  }

  for (int s = 0; s < 2; ++s) {
    transp16<<<dim3(8, 8, 64), 256, 0, stream>>>(h16, zht);
    {  // A (x1, batched): a*2^-4 = (adj@h+ba)*2^-4, split store
      Desc d{};
      d.A[0] = adj16; d.B[0] = zht;
      d.bias1 = ba_; d.o16 = a_hi; d.o16b = a_lo;
      gemw<1, 1><<<512, 512, 0, stream>>>(d);
    }
    {  // Z (x2): z = relu(a@Wz + h@Uz + bz)
      Desc d{};
      d.A[0] = a_hi; d.B[0] = Wz1;
      d.A[1] = h16;  d.B[1] = Uz1;
      d.bias1 = bz_; d.o16 = zht;
      gemw<2, 2><<<512, 512, 0, stream>>>(d);
    }
    {  // R (x4): rh = relu(a@Wr + h@Ur + br)*h, split store
      Desc d{};
      d.A[0] = a_hi; d.B[0] = Wr_h;
      d.A[1] = a_hi; d.B[1] = Wr_l;
      d.A[2] = a_lo; d.B[2] = Wr_h;
      d.A[3] = h16;  d.B[3] = Ur1;
      d.bias1 = br_; d.hf32 = hf; d.o16 = rh_hi; d.o16b = rh_lo;
      gemw<3, 4><<<512, 512, 0, stream>>>(d);
    }
    if (s == 0) {  // GRU step 1 (x6): full split
      Desc d{};
      d.A[0] = a_hi;  d.B[0] = Wh_h;
      d.A[1] = a_hi;  d.B[1] = Wh_l;
      d.A[2] = a_lo;  d.B[2] = Wh_h;
      d.A[3] = rh_hi; d.B[3] = Uh_h;
      d.A[4] = rh_hi; d.B[4] = Uh_l;
      d.A[5] = rh_lo; d.B[5] = Uh_h;
      d.bias1 = bh_; d.mask = mask; d.hf32 = hf; d.z16 = zht;
      d.outf = hf; d.o16 = h16;
      gemw<4, 6><<<512, 512, 0, stream>>>(d);
    } else {       // GRU step 2 (x2): inherited error dominates
      Desc d{};
      d.A[0] = a_hi;  d.B[0] = Wh_h;
      d.A[1] = rh_hi; d.B[1] = Uh_h;
      d.bias1 = bh_; d.mask = mask; d.hf32 = hf; d.z16 = zht;
      d.outf = hf; d.o16 = h16;
      gemw<4, 2><<<512, 512, 0, stream>>>(d);
    }
  }
}

// Round 15
// 740.044 us; speedup vs baseline: 1.6090x; 1.6090x over previous
//
#include <hip/hip_runtime.h>

// GGNN layer, B=64, N=512, D=512, steps=2. Numerics = rounds 6-10 pass set
// (fp16 + power-of-2 scaling, split passes on r/hc path; absmax 131072).
// r15: byte-optimal geometry (BM=BN=256, grid 256 -> 128MB/pass) + counted
// vmcnt ring-3 (r9's 6.5 TB/s) + pair-reuse plans (r10, -20% bytes) +
// race-safe barriers (r12). 1024 thr / 16 waves, wave 64x64, acc 64 VGPR.

#define LD 512
#define NNL ((long)LD * LD)
#define BARRIER do { asm volatile("s_barrier" ::: "memory"); \
                     __builtin_amdgcn_sched_barrier(0); } while (0)

typedef unsigned short u16;
typedef _Float16 f16;
typedef f16 f16x8 __attribute__((ext_vector_type(8)));
typedef float f32x4 __attribute__((ext_vector_type(4)));

__device__ __forceinline__ u16 f2h(float f) { f16 h = (f16)f; return *(u16*)&h; }
__device__ __forceinline__ float h2f(u16 b) { f16 h = *(f16*)&b; return (float)h; }

__device__ __forceinline__ void gload16(const void* g, void* l) {
  __builtin_amdgcn_global_load_lds(
      (const __attribute__((address_space(1))) void*)g,
      (__attribute__((address_space(3))) void*)l, 16, 0, 0);
}

__device__ __forceinline__ void vwaitN(int n) {  // n constant-folds after unroll
  if (n == 4)      asm volatile("s_waitcnt vmcnt(4)" ::: "memory");
  else if (n == 3) asm volatile("s_waitcnt vmcnt(3)" ::: "memory");
  else if (n == 2) asm volatile("s_waitcnt vmcnt(2)" ::: "memory");
  else if (n == 1) asm volatile("s_waitcnt vmcnt(1)" ::: "memory");
  else             asm volatile("s_waitcnt vmcnt(0)" ::: "memory");
}

// ---------------- f32 -> f16 single ----------------
__global__ void cvt_f16(const float* __restrict__ in, u16* __restrict__ out, int n4) {
  int i = blockIdx.x * blockDim.x + threadIdx.x;
  if (i >= n4) return;
  float4 v = reinterpret_cast<const float4*>(in)[i];
  ushort4 o;
  o.x = f2h(v.x); o.y = f2h(v.y); o.z = f2h(v.z); o.w = f2h(v.w);
  reinterpret_cast<ushort4*>(out)[i] = o;
}

// ---------------- f32 -> f16 hi/lo split ----------------
__global__ void cvt2h(const float* __restrict__ in, u16* __restrict__ ohi,
                      u16* __restrict__ olo, int n4) {
  int i = blockIdx.x * blockDim.x + threadIdx.x;
  if (i >= n4) return;
  float4 v = reinterpret_cast<const float4*>(in)[i];
  ushort4 h, l;
  h.x = f2h(v.x); l.x = f2h(v.x - h2f(h.x));
  h.y = f2h(v.y); l.y = f2h(v.y - h2f(h.y));
  h.z = f2h(v.z); l.z = f2h(v.z - h2f(h.z));
  h.w = f2h(v.w); l.w = f2h(v.w - h2f(h.w));
  reinterpret_cast<ushort4*>(ohi)[i] = h;
  reinterpret_cast<ushort4*>(olo)[i] = l;
}

// ------- weight f32 [K][N] -> f16 single (scaled), transposed [N][K] -------
__global__ void wconv1(const float* __restrict__ in, u16* __restrict__ out, float scale) {
  __shared__ float sm[32][33];
  int tx = threadIdx.x & 31, ty = threadIdx.x >> 5;
  int k0 = blockIdx.y * 32, n0 = blockIdx.x * 32;
#pragma unroll
  for (int i = 0; i < 32; i += 8)
    sm[ty + i][tx] = in[(size_t)(k0 + ty + i) * LD + n0 + tx];
  __syncthreads();
#pragma unroll
  for (int i = 0; i < 32; i += 8)
    out[(size_t)(n0 + ty + i) * LD + k0 + tx] = f2h(sm[tx][ty + i] * scale);
}

// ------- weight f32 [K][N] -> f16 hi/lo (scaled), transposed [N][K] -------
__global__ void wconv2h(const float* __restrict__ in, u16* __restrict__ ohi,
                        u16* __restrict__ olo, float scale) {
  __shared__ float sm[32][33];
  int tx = threadIdx.x & 31, ty = threadIdx.x >> 5;
  int k0 = blockIdx.y * 32, n0 = blockIdx.x * 32;
#pragma unroll
  for (int i = 0; i < 32; i += 8)
    sm[ty + i][tx] = in[(size_t)(k0 + ty + i) * LD + n0 + tx];
  __syncthreads();
#pragma unroll
  for (int i = 0; i < 32; i += 8) {
    float v = sm[tx][ty + i] * scale;
    u16 hi = f2h(v);
    size_t o = (size_t)(n0 + ty + i) * LD + k0 + tx;
    ohi[o] = hi;
    olo[o] = f2h(v - h2f(hi));
  }
}

// -------- u16 transpose per batch: [B][N][D] -> [B][D][N] --------
__global__ void transp16(const u16* __restrict__ in, u16* __restrict__ out) {
  __shared__ u16 sm[64][65];
  int b = blockIdx.z;
  int n0 = blockIdx.y * 64, d0 = blockIdx.x * 64;
  int lane = threadIdx.x & 63, grp = threadIdx.x >> 6;
  const u16* src = in + ((size_t)b * LD + n0) * LD + d0;
#pragma unroll
  for (int i = grp; i < 64; i += 4)
    sm[i][lane] = src[(size_t)i * LD + lane];
  __syncthreads();
  u16* dst = out + ((size_t)b * LD + d0) * LD + n0;
#pragma unroll
  for (int i = grp; i < 64; i += 4)
    dst[(size_t)i * LD + lane] = sm[lane][i];
}

// -------- pair plans (r10-verified): AI/BI operand idx, SA/SB stage flags --------
struct LENC {  // (x_lo,Weh),(x_hi,Weh),(x_hi,Wel)
  enum { P = 3 };
  static constexpr int AI[3] = {0, 1, 1}, BI[3] = {0, 0, 1};
  static constexpr int SA[3] = {1, 1, 0}, SB[3] = {1, 0, 1};
};
struct LA {    // (adj,ht)
  enum { P = 1 };
  static constexpr int AI[1] = {0}, BI[1] = {0};
  static constexpr int SA[1] = {1}, SB[1] = {1};
};
struct LZ {    // (a_hi,Wz),(h,Uz)
  enum { P = 2 };
  static constexpr int AI[2] = {0, 1}, BI[2] = {0, 1};
  static constexpr int SA[2] = {1, 1}, SB[2] = {1, 1};
};
struct LR {    // (a_hi,Wr_l),(a_hi,Wr_h),(a_lo,Wr_h),(h,Ur)
  enum { P = 4 };
  static constexpr int AI[4] = {0, 0, 1, 2}, BI[4] = {0, 1, 1, 2};
  static constexpr int SA[4] = {1, 0, 1, 1}, SB[4] = {1, 1, 0, 1};
};
struct LG1 {   // (a_hi,Wh_l),(a_hi,Wh_h),(a_lo,Wh_h),(rh_lo,Uh_h),(rh_hi,Uh_h),(rh_hi,Uh_l)
  enum { P = 6 };
  static constexpr int AI[6] = {0, 0, 1, 2, 3, 3}, BI[6] = {0, 1, 1, 2, 2, 3};
  static constexpr int SA[6] = {1, 0, 1, 1, 1, 0}, SB[6] = {1, 1, 0, 1, 0, 1};
};
struct LG2 {   // (a_hi,Wh_h),(rh_hi,Uh_h)
  enum { P = 2 };
  static constexpr int AI[2] = {0, 1}, BI[2] = {0, 1};
  static constexpr int SA[2] = {1, 1}, SB[2] = {1, 1};
};

// EPI 0 ENC: v=relu(acc+b1)*mask[row]   -> outf, o16=v*2^-4
// EPI 1 A  : v=acc+b1*2^-4 (batched)    -> o16=hi, o16b=lo
// EPI 2 Z  : v=relu(acc+b1)             -> o16=v*2^-4
// EPI 3 R  : v=relu(acc+b1)*hf32[idx]   -> o16=hi(v*2^-12), o16b=lo
// EPI 4 GRU: hc=tanh(acc+b1)*mask; z=16*z16[idx]; hn=(1-z)*hf32+z*hc -> outf, o16
struct Desc {
  const u16* Aop[4];
  const u16* Bop[4];
  const float* bias1;
  const float* mask;
  const float* hf32;
  const u16* z16;
  float* outf;
  u16* o16;
  u16* o16b;
};

template <int EPI, class PL>
__global__ __launch_bounds__(1024, 4) void gemr(Desc d) {
  constexpr int P = PL::P;
  constexpr int NQ = 16 * P;  // total K-tiles across all passes

  __shared__ __align__(16) u16 Aring[3 * 8192];  // 3 x 256x32 f16 (48 KiB)
  __shared__ __align__(16) u16 Bring[3 * 8192];  // 3 x 256x32 f16 (48 KiB)

  const int t = threadIdx.x;
  const int lane = t & 63;
  const int wid = t >> 6;                 // 16 waves
  const int wr = wid >> 2, wc = wid & 3;  // 4x4, wave = 64x64 of C

  // XCD-aware swizzle over 256 blocks (32/XCD); rowb -> XCD invariant
  const int id = (int)blockIdx.x;
  const int swz = (id & 7) * 32 + (id >> 3);
  const int colb = swz & 1;
  const int rowb = swz >> 1;  // 0..127
  size_t baseA, baseB;
  int rowBase0;
  if (EPI == 1) {
    const size_t bz = (size_t)(rowb >> 1);
    baseA = bz * NNL + (size_t)(rowb & 1) * 256 * LD;
    baseB = bz * NNL + (size_t)colb * 256 * LD;
    rowBase0 = (int)bz * 512 + (rowb & 1) * 256;
  } else {
    baseA = (size_t)rowb * 256 * LD;
    baseB = (size_t)colb * 256 * LD;
    rowBase0 = rowb * 256;
  }

  // staging: thread t -> 16B chunk t of the 16KB tile; row r=t>>2, dest
  // chunk t&3; source k-chunk XOR-pre-swizzled (rule 21: LDS dest linear)
  const int sr = t >> 2;
  const int sg = ((t & 3) ^ ((sr & 3) ^ ((sr >> 2) & 3))) * 8;

  auto stA = [&](const u16* op, int kb, int slot) {
    gload16(op + baseA + (size_t)sr * LD + kb + sg, Aring + slot * 8192 + t * 8);
  };
  auto stB = [&](const u16* op, int kb, int slot) {
    gload16(op + baseB + (size_t)sr * LD + kb + sg, Bring + slot * 8192 + t * 8);
  };

  // ds-read: frag row R, k-chunk lk stored at chunk lk ^ m(R);
  // m(R)=(R&3)^((R>>2)&3), invariant under R+16.
  const int lk = lane >> 4;
  const int RA = wr * 64 + (lane & 15);
  const int RB = wc * 64 + (lane & 15);
  const int aoff = RA * 32 + ((lk ^ ((RA & 3) ^ ((RA >> 2) & 3))) * 8);
  const int boff = RB * 32 + ((lk ^ ((RB & 3) ^ ((RB >> 2) & 3))) * 8);

  f32x4 acc[4][4] = {};

  // prologue: stage tiles q0, q1; wait so q0 is landed
  stA(d.Aop[PL::AI[0]], 0, 0);
  stB(d.Bop[PL::BI[0]], 0, 0);
  {
    constexpr int p1c = 1 % P;
    constexpr int kb1 = (1 / P) * 32;
    if (PL::SA[p1c]) stA(d.Aop[PL::AI[p1c]], kb1, 1);
    if (PL::SB[p1c]) stB(d.Bop[PL::BI[p1c]], kb1, 1);
    vwaitN(PL::SA[p1c] + PL::SB[p1c]);
  }
  BARRIER;

  int rA = 0, rB = 0;
  for (int kk = 0; kk < 16; ++kk) {
#pragma unroll
    for (int p = 0; p < P; ++p) {
      const int q = kk * P + p;
      const int p1 = (p + 1) % P, p2 = (p + 2) % P;
      const int kb2 = (p + 2 < P) ? kk * 32 : (p + 2 < 2 * P) ? (kk + 1) * 32 : (kk + 2) * 32;
      const bool st2 = (q + 2) < NQ;

      f16x8 af[4], bf[4];
      {
        const u16* As_ = Aring + rA * 8192;
        const u16* Bs_ = Bring + rB * 8192;
#pragma unroll
        for (int i = 0; i < 4; ++i) af[i] = *(const f16x8*)&As_[aoff + i * 512];
#pragma unroll
        for (int j = 0; j < 4; ++j) bf[j] = *(const f16x8*)&Bs_[boff + j * 512];
      }
      if (st2) {
        if (PL::SA[p2]) stA(d.Aop[PL::AI[p2]], kb2, (rA + PL::SA[p1] + 1) % 3);
        if (PL::SB[p2]) stB(d.Bop[PL::BI[p2]], kb2, (rB + PL::SB[p1] + 1) % 3);
      }
      __builtin_amdgcn_s_setprio(1);
#pragma unroll
      for (int i = 0; i < 4; ++i)
#pragma unroll
        for (int j = 0; j < 4; ++j)
          acc[i][j] = __builtin_amdgcn_mfma_f32_16x16x32_f16(af[i], bf[j], acc[i][j], 0, 0, 0);
      __builtin_amdgcn_s_setprio(0);
      vwaitN(st2 ? PL::SA[p2] + PL::SB[p2] : 0);
      BARRIER;
      rA = (rA + PL::SA[p1]) % 3;
      rB = (rB + PL::SB[p1]) % 3;
    }
  }

  // epilogue: C/D layout col=lane&15, row=(lane>>4)*4+reg [m89-verified]
  const float S4 = 0.0625f;          // 2^-4
  const float S12 = 2.44140625e-4f;  // 2^-12
  const int rowBase = rowBase0 + wr * 64 + (lane >> 4) * 4;
  const int colBase = colb * 256 + wc * 64 + (lane & 15);
#pragma unroll
  for (int i = 0; i < 4; ++i) {
#pragma unroll
    for (int j = 0; j < 4; ++j) {
      const int col = colBase + j * 16;
      const float bv = d.bias1[col];
#pragma unroll
      for (int r = 0; r < 4; ++r) {
        const int row = rowBase + i * 16 + r;
        const size_t idx = (size_t)row * LD + col;
        const float a = acc[i][j][r];
        if (EPI == 0) {
          float v = fmaxf(a + bv, 0.0f) * d.mask[row];
          d.outf[idx] = v;
          d.o16[idx] = f2h(v * S4);
        } else if (EPI == 1) {
          float v = a + bv * S4;
          u16 hi = f2h(v);
          d.o16[idx] = hi;
          d.o16b[idx] = f2h(v - h2f(hi));
        } else if (EPI == 2) {
          float v = fmaxf(a + bv, 0.0f);
          d.o16[idx] = f2h(v * S4);
        } else if (EPI == 3) {
          float v = fmaxf(a + bv, 0.0f) * d.hf32[idx];
          u16 hi = f2h(v * S12);
          d.o16[idx] = hi;
          float rec = h2f(hi) * 4096.0f;
          d.o16b[idx] = f2h((v - rec) * S12);
        } else {
          float hc = tanhf(a + bv) * d.mask[row];
          float z = 16.0f * h2f(d.z16[idx]);
          float h = d.hf32[idx];
          float hn = (1.0f - z) * h + z * hc;
          d.outf[idx] = hn;
          d.o16[idx] = f2h(hn * S4);
        }
      }
    }
  }
}

extern "C" void kernel_launch(void* const* d_in, const int* in_sizes, int n_in,
                              void* d_out, int out_size, void* d_ws, size_t ws_size,
                              hipStream_t stream) {
  const float* x    = (const float*)d_in[0];
  const float* adj  = (const float*)d_in[1];
  const float* mask = (const float*)d_in[2];
  const float* Wenc = (const float*)d_in[3];
  const float* benc = (const float*)d_in[4];
  const float* Wz   = (const float*)d_in[5];
  const float* Uz   = (const float*)d_in[6];
  const float* bz_  = (const float*)d_in[7];
  const float* Wr   = (const float*)d_in[8];
  const float* Ur   = (const float*)d_in[9];
  const float* br_  = (const float*)d_in[10];
  const float* Wh   = (const float*)d_in[11];
  const float* Uh   = (const float*)d_in[12];
  const float* bh_  = (const float*)d_in[13];
  const float* ba_  = (const float*)d_in[14];

  float* hf = (float*)d_out;  // h in f32 across steps (64 MiB)

  const size_t SZ  = (size_t)64 * 512 * 512 * sizeof(u16);  // 32 MiB
  const size_t WSZ = (size_t)LD * LD * sizeof(u16);         // 0.5 MiB
  const size_t NEED = 7 * SZ + 11 * WSZ;                    // 229.5 MiB
  if (ws_size < NEED) return;

  char* p = (char*)d_ws;
  u16* adj16 = (u16*)p; p += SZ;
  u16* h16   = (u16*)p; p += SZ;   // h * 2^-4
  u16* a_hi  = (u16*)p; p += SZ;   // a*2^-4 hi ; aliased: x_hi before encoder
  u16* a_lo  = (u16*)p; p += SZ;   // a*2^-4 lo ; aliased: x_lo before encoder
  u16* zht   = (u16*)p; p += SZ;   // h^T*2^-4 (transp..A), then z*2^-4 (Z..GRU)
  u16* rh_hi = (u16*)p; p += SZ;   // rh*2^-12 hi
  u16* rh_lo = (u16*)p; p += SZ;   // rh*2^-12 lo
  u16* w     = (u16*)p;
  u16* We_h = w + 0 * LD * LD;  u16* We_l = w + 1 * LD * LD;   // x1
  u16* Wz1  = w + 2 * LD * LD;                                  // x16
  u16* Uz1  = w + 3 * LD * LD;                                  // x16
  u16* Wr_h = w + 4 * LD * LD;  u16* Wr_l = w + 5 * LD * LD;   // x16
  u16* Ur1  = w + 6 * LD * LD;                                  // x16
  u16* Wh_h = w + 7 * LD * LD;  u16* Wh_l = w + 8 * LD * LD;   // x16
  u16* Uh_h = w + 9 * LD * LD;  u16* Uh_l = w + 10 * LD * LD;  // x4096
  u16* x_hi = a_hi;
  u16* x_lo = a_lo;

  const int NELT = 64 * 512 * 512;
  cvt2h<<<NELT / 4 / 256, 256, 0, stream>>>(x, x_hi, x_lo, NELT / 4);
  cvt_f16<<<NELT / 4 / 256, 256, 0, stream>>>(adj, adj16, NELT / 4);

  dim3 wg(16, 16);
  wconv2h<<<wg, 256, 0, stream>>>(Wenc, We_h, We_l, 1.0f);
  wconv1<<<wg, 256, 0, stream>>>(Wz, Wz1, 16.0f);
  wconv1<<<wg, 256, 0, stream>>>(Uz, Uz1, 16.0f);
  wconv2h<<<wg, 256, 0, stream>>>(Wr, Wr_h, Wr_l, 16.0f);
  wconv1<<<wg, 256, 0, stream>>>(Ur, Ur1, 16.0f);
  wconv2h<<<wg, 256, 0, stream>>>(Wh, Wh_h, Wh_l, 16.0f);
  wconv2h<<<wg, 256, 0, stream>>>(Uh, Uh_h, Uh_l, 4096.0f);

  // ENC: h0 = mask*relu(x@Wenc+benc)
  {
    Desc d{};
    d.Aop[0] = x_lo; d.Aop[1] = x_hi;
    d.Bop[0] = We_h; d.Bop[1] = We_l;
    d.bias1 = benc; d.mask = mask; d.outf = hf; d.o16 = h16;
    gemr<0, LENC><<<256, 1024, 0, stream>>>(d);
  }

  for (int s = 0; s < 2; ++s) {
    transp16<<<dim3(8, 8, 64), 256, 0, stream>>>(h16, zht);
    {  // A (batched): a*2^-4 = (adj@h+ba)*2^-4, split store
      Desc d{};
      d.Aop[0] = adj16; d.Bop[0] = zht;
      d.bias1 = ba_; d.o16 = a_hi; d.o16b = a_lo;
      gemr<1, LA><<<256, 1024, 0, stream>>>(d);
    }
    {  // Z: z = relu(a@Wz + h@Uz + bz)
      Desc d{};
      d.Aop[0] = a_hi; d.Aop[1] = h16;
      d.Bop[0] = Wz1;  d.Bop[1] = Uz1;
      d.bias1 = bz_; d.o16 = zht;
      gemr<2, LZ><<<256, 1024, 0, stream>>>(d);
    }
    {  // R: rh = relu(a@Wr + h@Ur + br)*h, split store
      Desc d{};
      d.Aop[0] = a_hi; d.Aop[1] = a_lo; d.Aop[2] = h16;
      d.Bop[0] = Wr_l; d.Bop[1] = Wr_h; d.Bop[2] = Ur1;
      d.bias1 = br_; d.hf32 = hf; d.o16 = rh_hi; d.o16b = rh_lo;
      gemr<3, LR><<<256, 1024, 0, stream>>>(d);
    }
    if (s == 0) {  // GRU step 1: full split (LG1 order)
      Desc d{};
      d.Aop[0] = a_hi; d.Aop[1] = a_lo; d.Aop[2] = rh_lo; d.Aop[3] = rh_hi;
      d.Bop[0] = Wh_l; d.Bop[1] = Wh_h; d.Bop[2] = Uh_h;  d.Bop[3] = Uh_l;
      d.bias1 = bh_; d.mask = mask; d.hf32 = hf; d.z16 = zht;
      d.outf = hf; d.o16 = h16;
      gemr<4, LG1><<<256, 1024, 0, stream>>>(d);
    } else {       // GRU step 2: inherited error dominates
      Desc d{};
      d.Aop[0] = a_hi; d.Aop[1] = rh_hi;
      d.Bop[0] = Wh_h; d.Bop[1] = Uh_h;
      d.bias1 = bh_; d.mask = mask; d.hf32 = hf; d.z16 = zht;
      d.outf = hf; d.o16 = h16;
      gemr<4, LG2><<<256, 1024, 0, stream>>>(d);
    }
  }
}